// Round 2
// baseline (264.384 us; speedup 1.0000x reference)
//
#include <hip/hip_runtime.h>
#include <hip/hip_fp16.h>

// GCN 2-layer. count (+rank) -> multi-block shfl-scan (fused rsqrt) ->
// [fused scan_fix || MFMA gemm1] -> atomic-free CSR fill -> sliced agg1 ->
// gemm2 -> sliced agg2.
// out[i] = dis[i]*(scaled[i] + sum_j scaled[j]) + b, scaled[j]=dis[j]*(x@W)[j].
//
// r13: XCD-L2-resident sliced aggregation. The agg gathers previously read
// random 256B/128B rows from 12.8MB/6.4MB tables -> ~70% served by L3
// (per-XCD L2 = 4MB, hit rate ~30%). Now the GEMMs emit feature-SLICED
// tables ([slice][node][16]), and agg blocks are pinned slice=blockIdx%8
// (round-robin XCD dispatch) so each XCD gathers only from its own 1.6MB
// slice -> L2-resident. Gather instrs stay fully packed: 2 lanes per 32B
// row-slice, 8 edges/quad/iter, shfl_xor pair-reduction at the end. csr is
// read nontemporal (8x re-read must not evict the table).
// r14: identical resubmit (r13 bench was an infra failure, no verdict).
// History: r7 weighted-CSR int2 -11us (reverted); r9 one-block scan 133us
// (reverted); r11 degree-bucket perm: atomic-contention disaster, falsified
// batching-inflation theory; r12 = shfl scan + fix||gemm1 fusion (203us).

typedef _Float16 half8 __attribute__((ext_vector_type(8)));
typedef float floatx4 __attribute__((ext_vector_type(4)));

__global__ void k_count(const int* __restrict__ col, int* __restrict__ deg,
                        int* __restrict__ rank, int E) {
    int e = blockIdx.x * blockDim.x + threadIdx.x;
    if (e < E) rank[e] = atomicAdd(&deg[col[e]], 1);
}

// Per-chunk inclusive scan via wave shfl (2 barriers) + dis = rsqrt(deg+1).
__global__ __launch_bounds__(1024) void k_scan_local(const int* __restrict__ deg,
                                                     int* __restrict__ rowptr,
                                                     int* __restrict__ bsum,
                                                     float* __restrict__ dis, int n) {
    __shared__ int wsum[16];
    int b = blockIdx.x, tid = threadIdx.x;
    int lane = tid & 63, w = tid >> 6;
    int i = b * 1024 + tid;
    int v = (i < n) ? deg[i] : 0;
    if (i < n) dis[i] = rsqrtf((float)v + 1.0f);  // +1 = self-loop
    int sc = v;
#pragma unroll
    for (int off = 1; off < 64; off <<= 1) {
        int t = __shfl_up(sc, off);
        if (lane >= off) sc += t;
    }
    if (lane == 63) wsum[w] = sc;
    __syncthreads();
    if (w == 0) {
        int s = (lane < 16) ? wsum[lane] : 0;
#pragma unroll
        for (int off = 1; off < 16; off <<= 1) {
            int t = __shfl_up(s, off);
            if (lane >= off) s += t;
        }
        if (lane < 16) wsum[lane] = s;
    }
    __syncthreads();
    int incl = sc + ((w > 0) ? wsum[w - 1] : 0);
    if (i < n) rowptr[i + 1] = incl;
    if (tid == 1023) bsum[b] = incl;
    if (b == 0 && tid == 0) rowptr[0] = 0;
}

// Y_sliced[k/16 -> slice][M][16](fp16) = (X[M,128] @ W[128,N]) * scale[m].
// Block: 64 rows (4 waves x 16), all N cols. K=128 in 4 MFMA steps of 32.
// LDS Wt[n][k] fp16 as half2 dwords; 16B block (n,kblk) at dword
// n*64 + (kblk ^ (n&15))*4 (XOR swizzle -> <=2-way banks on b128 reads).
// Frags (m89/m118/m120): A[m=lane&15][k=quad*8+j], B[k=quad*8+j][n=lane&15],
// D row=quad*4+reg, col=lane&15.
// SA: A is itself sliced [8][M][16] (the layer-1 agg output layout).
template <int N, typename AT, bool SA>
__device__ __forceinline__ void gemm_tile(const AT* __restrict__ X,
                                          const float* __restrict__ W,
                                          const float* __restrict__ scale,
                                          __half* __restrict__ Y, int M,
                                          int m0, __half2* wt, int tid) {
    for (int i = tid; i < N * 64; i += 256) {
        int nn = i & (N - 1);
        int k2 = i / N;  // k = 2*k2
        float w0 = W[(size_t)(2 * k2) * N + nn];
        float w1 = W[(size_t)(2 * k2 + 1) * N + nn];
        wt[nn * 64 + ((k2 >> 2) ^ (nn & 15)) * 4 + (k2 & 3)] = __floats2half2_rn(w0, w1);
    }
    __syncthreads();
    int wid = tid >> 6, lane = tid & 63;
    int col = lane & 15, quad = lane >> 4;
    int m_a = m0 + wid * 16 + col;
    bool a_ok = m_a < M;
    constexpr int NT = N / 16;
    floatx4 acc[NT] = {};
#pragma unroll
    for (int ks = 0; ks < 4; ++ks) {
        int k = ks * 32 + quad * 8;
        half8 af;
        if constexpr (sizeof(AT) == 4) {
            floatx4 a0 = {0.f, 0.f, 0.f, 0.f}, a1 = {0.f, 0.f, 0.f, 0.f};
            if (a_ok) {
                a0 = *(const floatx4*)&X[(size_t)m_a * 128 + k];
                a1 = *(const floatx4*)&X[(size_t)m_a * 128 + k + 4];
            }
            af = half8{(_Float16)a0[0], (_Float16)a0[1], (_Float16)a0[2], (_Float16)a0[3],
                       (_Float16)a1[0], (_Float16)a1[1], (_Float16)a1[2], (_Float16)a1[3]};
        } else if constexpr (SA) {
            // sliced A: element (m,k) at [(k>>4)*M + m]*16 + (k&15)
            int slice = ks * 2 + (quad >> 1);
            half8 t = {};
            if (a_ok)
                t = *(const half8*)(const void*)&X[((size_t)slice * M + m_a) * 16 + (quad & 1) * 8];
            af = t;
        } else {
            half8 t = {};
            if (a_ok) t = *(const half8*)(const void*)&X[(size_t)m_a * 128 + k];
            af = t;
        }
        int kblk = ks * 4 + quad;
#pragma unroll
        for (int nt = 0; nt < NT; ++nt) {
            int nn = nt * 16 + col;
            half8 bf = *(const half8*)(const void*)&wt[nn * 64 + (kblk ^ (nn & 15)) * 4];
            acc[nt] = __builtin_amdgcn_mfma_f32_16x16x32_f16(af, bf, acc[nt], 0, 0, 0);
        }
    }
    int mbase = m0 + wid * 16 + quad * 4;
    float s[4];
#pragma unroll
    for (int r = 0; r < 4; ++r) s[r] = (mbase + r < M) ? scale[mbase + r] : 0.f;
#pragma unroll
    for (int nt = 0; nt < NT; ++nt) {
#pragma unroll
        for (int r = 0; r < 4; ++r) {
            if (mbase + r < M)
                Y[((size_t)nt * M + (mbase + r)) * 16 + col] = __float2half(acc[nt][r] * s[r]);
        }
    }
}

// Fused: blocks [0,FB) apply scan_fix (cross-chunk prefix); blocks [FB,...)
// run gemm1. Independent inputs; scan_fix is only ~49 blocks so the 32KB
// LDS can't occupancy-starve it.
__global__ __launch_bounds__(256) void k_fix_gemm1(int* __restrict__ rowptr,
                                                   const int* __restrict__ bsum, int n,
                                                   const float* __restrict__ X,
                                                   const float* __restrict__ W,
                                                   const float* __restrict__ scale,
                                                   __half* __restrict__ Y, int M, int FB) {
    __shared__ __align__(16) __half2 wt[128 * 64];  // 32 KB (gemm); reused by fix
    int b = blockIdx.x, tid = threadIdx.x;
    if (b < FB) {
        int* red = (int*)wt;
        int partial = 0;
        for (int j = tid; j < b; j += 256) partial += bsum[j];
        red[tid] = partial;
        __syncthreads();
        for (int off = 128; off > 0; off >>= 1) {
            if (tid < off) red[tid] += red[tid + off];
            __syncthreads();
        }
        int offv = red[0];
        if (offv == 0) return;
#pragma unroll
        for (int r = 0; r < 4; ++r) {
            int i = b * 1024 + r * 256 + tid;
            if (i < n) rowptr[i + 1] += offv;
        }
        return;
    }
    gemm_tile<128, float, false>(X, W, scale, Y, M, (b - FB) * 64, wt, tid);
}

__global__ __launch_bounds__(256) void k_gemm2(const __half* __restrict__ X,
                                               const float* __restrict__ W,
                                               const float* __restrict__ scale,
                                               __half* __restrict__ Y, int M) {
    __shared__ __align__(16) __half2 wt[64 * 64];  // 16 KB
    gemm_tile<64, __half, true>(X, W, scale, Y, M, blockIdx.x * 64, wt, threadIdx.x);
}

// Atomic-free: position = rowptr[target] + precomputed rank.
__global__ void k_fill(const int* __restrict__ row, const int* __restrict__ col,
                       const int* __restrict__ rowptr, const int* __restrict__ rank,
                       int* __restrict__ csr, int E) {
    int e = blockIdx.x * blockDim.x + threadIdx.x;
    if (e < E) csr[rowptr[col[e]] + rank[e]] = row[e];
}

// Sliced agg, layer 1 (128 feats = 8 slices x 16). slice = blockIdx%8 ->
// pinned to one XCD (round-robin dispatch); slice table = 1.6MB, L2-resident.
// Quad (16 lanes) per node: 8 lane-pairs gather 8 edges/iter (32B row-slice,
// 16B/lane -> gather instr fully packed), shfl_xor pair-reduce at the end.
// csr loads nontemporal so the 8x re-read streams past L2.
__global__ __launch_bounds__(256) void k_agg1s(const __half* __restrict__ xw,  // [8][n][16]
                                               const float* __restrict__ dis,
                                               const int* __restrict__ rowptr,
                                               const int* __restrict__ csr,
                                               const float* __restrict__ bias,
                                               __half* __restrict__ h,  // [8][n][16]
                                               int n) {
    int b = blockIdx.x;
    int s = b & 7, chunk = b >> 3;
    int tid = threadIdx.x, lane = tid & 63;
    int q = lane >> 4, li = lane & 15;
    int qbase = lane & 48;
    int node = chunk * 16 + ((tid >> 6) << 2) + q;
    bool ok = node < n;
    float di = 0.f;
    int beg = 0, end = 0;
    if (ok) {
        di = dis[node];
        beg = rowptr[node];
        end = rowptr[node + 1];
    }
    int dg = end - beg;
    int m1 = max(dg, __shfl(dg, lane ^ 16));
    int mx = max(m1, __shfl(m1, lane ^ 32));  // max over the wave's 4 nodes
    const half8* rows = (const half8*)(xw + (size_t)s * n * 16);  // 2 half8 per node
    int pr = li >> 1, hi = li & 1;
    float acc[8] = {};
    for (int i = 0; i < mx; i += 8) {
        int e = beg + i + (li & 7);
        int myidx = (li < 8 && e < end) ? __builtin_nontemporal_load(&csr[e]) : 0;
        int sj = __shfl(myidx, qbase + pr);  // this pair's source node
        half8 v = rows[(size_t)sj * 2 + hi];
        float m = ((beg + i + pr) < end) ? 1.f : 0.f;
#pragma unroll
        for (int f = 0; f < 8; ++f) acc[f] += m * (float)v[f];
    }
#pragma unroll
    for (int off = 2; off <= 8; off <<= 1) {
#pragma unroll
        for (int f = 0; f < 8; ++f) acc[f] += __shfl_xor(acc[f], off);
    }
    // lanes 0 (feats 0-7) and 1 (feats 8-15) of each quad hold the sums
    if (ok && li < 2) {
        half8 sf = rows[(size_t)node * 2 + li];
        floatx4 b0 = *(const floatx4*)&bias[s * 16 + li * 8];
        floatx4 b1 = *(const floatx4*)&bias[s * 16 + li * 8 + 4];
        half8 o;
#pragma unroll
        for (int f = 0; f < 4; ++f)
            o[f] = (_Float16)fmaxf((acc[f] + (float)sf[f]) * di + b0[f], 0.f);
#pragma unroll
        for (int f = 0; f < 4; ++f)
            o[4 + f] = (_Float16)fmaxf((acc[4 + f] + (float)sf[4 + f]) * di + b1[f], 0.f);
        __builtin_nontemporal_store(
            o, (half8*)(h + ((size_t)s * n + node) * 16 + li * 8));
    }
}

// Sliced agg, layer 2 (64 feats = 4 slices x 16; each slice pinned to an
// XCD pair via slice=(blockIdx%8)>>1, node chunks split by blockIdx&1).
// Output fp32 row-major [node][64]: 2 lanes x 32B = one full 64B sector.
__global__ __launch_bounds__(256) void k_agg2s(const __half* __restrict__ xw,  // [4][n][16]
                                               const float* __restrict__ dis,
                                               const int* __restrict__ rowptr,
                                               const int* __restrict__ csr,
                                               const float* __restrict__ bias,
                                               float* __restrict__ out, int n) {
    int b = blockIdx.x;
    int s = (b & 7) >> 1, chunk = ((b >> 3) << 1) | (b & 1);
    int tid = threadIdx.x, lane = tid & 63;
    int q = lane >> 4, li = lane & 15;
    int qbase = lane & 48;
    int node = chunk * 16 + ((tid >> 6) << 2) + q;
    bool ok = node < n;
    float di = 0.f;
    int beg = 0, end = 0;
    if (ok) {
        di = dis[node];
        beg = rowptr[node];
        end = rowptr[node + 1];
    }
    int dg = end - beg;
    int m1 = max(dg, __shfl(dg, lane ^ 16));
    int mx = max(m1, __shfl(m1, lane ^ 32));
    const half8* rows = (const half8*)(xw + (size_t)s * n * 16);
    int pr = li >> 1, hi = li & 1;
    float acc[8] = {};
    for (int i = 0; i < mx; i += 8) {
        int e = beg + i + (li & 7);
        int myidx = (li < 8 && e < end) ? __builtin_nontemporal_load(&csr[e]) : 0;
        int sj = __shfl(myidx, qbase + pr);
        half8 v = rows[(size_t)sj * 2 + hi];
        float m = ((beg + i + pr) < end) ? 1.f : 0.f;
#pragma unroll
        for (int f = 0; f < 8; ++f) acc[f] += m * (float)v[f];
    }
#pragma unroll
    for (int off = 2; off <= 8; off <<= 1) {
#pragma unroll
        for (int f = 0; f < 8; ++f) acc[f] += __shfl_xor(acc[f], off);
    }
    if (ok && li < 2) {
        half8 sf = rows[(size_t)node * 2 + li];
        floatx4 b0 = *(const floatx4*)&bias[s * 16 + li * 8];
        floatx4 b1 = *(const floatx4*)&bias[s * 16 + li * 8 + 4];
        floatx4 o0, o1;
#pragma unroll
        for (int f = 0; f < 4; ++f) o0[f] = (acc[f] + (float)sf[f]) * di + b0[f];
#pragma unroll
        for (int f = 0; f < 4; ++f) o1[f] = (acc[4 + f] + (float)sf[4 + f]) * di + b1[f];
        float* dst = out + (size_t)node * 64 + s * 16 + li * 8;
        __builtin_nontemporal_store(o0, (floatx4*)dst);
        __builtin_nontemporal_store(o1, (floatx4*)(dst + 4));
    }
}

extern "C" void kernel_launch(void* const* d_in, const int* in_sizes, int n_in,
                              void* d_out, int out_size, void* d_ws, size_t ws_size,
                              hipStream_t stream) {
    const float* x  = (const float*)d_in[0];
    const int*   ei = (const int*)d_in[1];
    const float* W1 = (const float*)d_in[2];
    const float* b1 = (const float*)d_in[3];
    const float* W2 = (const float*)d_in[4];
    const float* b2 = (const float*)d_in[5];
    float* out = (float*)d_out;

    const int n = in_sizes[0] / 128;   // 50000
    const int E = in_sizes[1] / 2;     // 800000
    const int* row = ei;
    const int* col = ei + E;
    const int NB = (n + 1023) / 1024;
    const int CB = (E + 255) / 256;
    const int GB = (n + 63) / 64;
    const int NCH = (n + 15) / 16;     // 16-node chunks for the sliced aggs

    char* ws = (char*)d_ws;
    size_t off = 0;
    auto alloc = [&](size_t bytes) -> void* {
        void* p = ws + off;
        off += (bytes + 255) & ~(size_t)255;
        return p;
    };
    int*    deg    = (int*)alloc((size_t)n * 4);
    int*    rowptr = (int*)alloc((size_t)(n + 1) * 4);
    int*    bsum   = (int*)alloc((size_t)NB * 4);
    int*    rank   = (int*)alloc((size_t)E * 4);
    int*    csr    = (int*)alloc((size_t)E * 4);
    float*  dis    = (float*)alloc((size_t)n * 4);
    __half* xw1    = (__half*)alloc((size_t)n * 128 * 2);  // sliced [8][n][16]
    __half* h      = (__half*)alloc((size_t)n * 128 * 2);  // sliced [8][n][16]
    __half* xw2    = (__half*)alloc((size_t)n * 64 * 2);   // sliced [4][n][16]
    (void)ws_size;

    hipMemsetAsync(deg, 0, (size_t)n * 4, stream);
    k_count<<<CB, 256, 0, stream>>>(col, deg, rank, E);
    k_scan_local<<<NB, 1024, 0, stream>>>(deg, rowptr, bsum, dis, n);
    k_fix_gemm1<<<NB + GB, 256, 0, stream>>>(rowptr, bsum, n, x, W1, dis, xw1, n, NB);
    k_fill<<<CB, 256, 0, stream>>>(row, col, rowptr, rank, csr, E);

    k_agg1s<<<NCH * 8, 256, 0, stream>>>(xw1, dis, rowptr, csr, b1, h, n);
    k_gemm2<<<GB, 256, 0, stream>>>(h, W2, dis, xw2, n);
    k_agg2s<<<((NCH + 1) / 2) * 8, 256, 0, stream>>>(xw2, dis, rowptr, csr, b2, out, n);
}

// Round 3
// 201.789 us; speedup vs baseline: 1.3102x; 1.3102x over previous
//
#include <hip/hip_runtime.h>
#include <hip/hip_fp16.h>

// GCN 2-layer. count (+rank) -> multi-block shfl-scan (fused rsqrt) ->
// [fused scan_fix || MFMA gemm1 || CSR fill] -> agg128 -> gemm2 -> agg64.
// out[i] = dis[i]*(scaled[i] + sum_j scaled[j]) + b, scaled[j]=dis[j]*(x@W)[j]
//
// r15: revert r13/r14 slicing (FALSIFIED: gather cost ~6.4 cy per unique
// 64B line per CU, independent of serving tier; 32B slices doubled line
// touches -> 1.56x slower. r12 row-contiguous layout = line-touch-optimal).
// New: fill is fused into the fix||gemm1 kernel as a third block range.
// fill no longer needs the fixed rowptr: it reads the RAW per-chunk scan
// (praw, a second copy so concurrent fix can't race) and adds the chunk
// prefix Q[b]=sum bsum[0..b-1], scanned per-block in LDS (49 entries, one
// wave). fill (scatter/latency-bound) overlaps gemm1 (MFMA-bound).
// History: r7 weighted-CSR int2 -11us (reverted); r9 one-block scan 133us
// (reverted); r11 degree-bucket perm: atomic-contention disaster; r12 =
// shfl scan + fix||gemm1 fusion (203us); r13/r14 sliced agg 264us (FALSIFIED).

typedef _Float16 half8 __attribute__((ext_vector_type(8)));
typedef float floatx4 __attribute__((ext_vector_type(4)));

__global__ void k_count(const int* __restrict__ col, int* __restrict__ deg,
                        int* __restrict__ rank, int E) {
    int e = blockIdx.x * blockDim.x + threadIdx.x;
    if (e < E) rank[e] = atomicAdd(&deg[col[e]], 1);
}

// Per-chunk inclusive scan via wave shfl (2 barriers) + dis = rsqrt(deg+1).
// Writes rowptr (to be globally fixed) AND praw (raw copy for the fused
// fill, which applies the chunk prefix itself).
__global__ __launch_bounds__(1024) void k_scan_local(const int* __restrict__ deg,
                                                     int* __restrict__ rowptr,
                                                     int* __restrict__ praw,
                                                     int* __restrict__ bsum,
                                                     float* __restrict__ dis, int n) {
    __shared__ int wsum[16];
    int b = blockIdx.x, tid = threadIdx.x;
    int lane = tid & 63, w = tid >> 6;
    int i = b * 1024 + tid;
    int v = (i < n) ? deg[i] : 0;
    if (i < n) dis[i] = rsqrtf((float)v + 1.0f);  // +1 = self-loop
    int sc = v;
#pragma unroll
    for (int off = 1; off < 64; off <<= 1) {
        int t = __shfl_up(sc, off);
        if (lane >= off) sc += t;
    }
    if (lane == 63) wsum[w] = sc;
    __syncthreads();
    if (w == 0) {
        int s = (lane < 16) ? wsum[lane] : 0;
#pragma unroll
        for (int off = 1; off < 16; off <<= 1) {
            int t = __shfl_up(s, off);
            if (lane >= off) s += t;
        }
        if (lane < 16) wsum[lane] = s;
    }
    __syncthreads();
    int incl = sc + ((w > 0) ? wsum[w - 1] : 0);
    if (i < n) {
        rowptr[i + 1] = incl;
        praw[i + 1] = incl;
    }
    if (tid == 1023) bsum[b] = incl;
    if (b == 0 && tid == 0) {
        rowptr[0] = 0;
        praw[0] = 0;
    }
}

// Y[M,N](fp16) = (X[M,128] @ W[128,N]) * scale[m].
// Block: 64 rows (4 waves x 16), all N cols. K=128 in 4 MFMA steps of 32.
// LDS Wt[n][k] fp16 as half2 dwords; 16B block (n,kblk) at dword
// n*64 + (kblk ^ (n&15))*4 (XOR swizzle -> <=2-way banks on b128 reads).
// Frags (m89/m118/m120): A[m=lane&15][k=quad*8+j], B[k=quad*8+j][n=lane&15],
// D row=quad*4+reg, col=lane&15.
template <int N, typename AT>
__device__ __forceinline__ void gemm_tile(const AT* __restrict__ X,
                                          const float* __restrict__ W,
                                          const float* __restrict__ scale,
                                          __half* __restrict__ Y, int M,
                                          int m0, __half2* wt, int tid) {
    for (int i = tid; i < N * 64; i += 256) {
        int nn = i & (N - 1);
        int k2 = i / N;  // k = 2*k2
        float w0 = W[(size_t)(2 * k2) * N + nn];
        float w1 = W[(size_t)(2 * k2 + 1) * N + nn];
        wt[nn * 64 + ((k2 >> 2) ^ (nn & 15)) * 4 + (k2 & 3)] = __floats2half2_rn(w0, w1);
    }
    __syncthreads();
    int wid = tid >> 6, lane = tid & 63;
    int col = lane & 15, quad = lane >> 4;
    int m_a = m0 + wid * 16 + col;
    bool a_ok = m_a < M;
    constexpr int NT = N / 16;
    floatx4 acc[NT] = {};
#pragma unroll
    for (int ks = 0; ks < 4; ++ks) {
        int k = ks * 32 + quad * 8;
        half8 af;
        if constexpr (sizeof(AT) == 4) {
            floatx4 a0 = {0.f, 0.f, 0.f, 0.f}, a1 = {0.f, 0.f, 0.f, 0.f};
            if (a_ok) {
                a0 = *(const floatx4*)&X[(size_t)m_a * 128 + k];
                a1 = *(const floatx4*)&X[(size_t)m_a * 128 + k + 4];
            }
            af = half8{(_Float16)a0[0], (_Float16)a0[1], (_Float16)a0[2], (_Float16)a0[3],
                       (_Float16)a1[0], (_Float16)a1[1], (_Float16)a1[2], (_Float16)a1[3]};
        } else {
            half8 t = {};
            if (a_ok) t = *(const half8*)(const void*)&X[(size_t)m_a * 128 + k];
            af = t;
        }
        int kblk = ks * 4 + quad;
#pragma unroll
        for (int nt = 0; nt < NT; ++nt) {
            int nn = nt * 16 + col;
            half8 bf = *(const half8*)(const void*)&wt[nn * 64 + (kblk ^ (nn & 15)) * 4];
            acc[nt] = __builtin_amdgcn_mfma_f32_16x16x32_f16(af, bf, acc[nt], 0, 0, 0);
        }
    }
    int mbase = m0 + wid * 16 + quad * 4;
    float s[4];
#pragma unroll
    for (int r = 0; r < 4; ++r) s[r] = (mbase + r < M) ? scale[mbase + r] : 0.f;
#pragma unroll
    for (int nt = 0; nt < NT; ++nt) {
#pragma unroll
        for (int r = 0; r < 4; ++r) {
            if (mbase + r < M)
                Y[(size_t)(mbase + r) * N + nt * 16 + col] = __float2half(acc[nt][r] * s[r]);
        }
    }
}

// Fused 3-range kernel:
//   blocks [0,FB):        scan_fix — add chunk prefix to rowptr (for aggs)
//   blocks [FB,FB+GB):    gemm1 (MFMA)
//   blocks [FB+GB,...):   CSR fill — pos = praw[c] + Q[(c-1)>>10] + rank[e],
//                         Q scanned from bsum in LDS (no dep on fix; praw is
//                         a separate copy so concurrent fix can't race).
// fill (scatter/latency-bound) overlaps gemm1 (MFMA/LDS-bound).
__global__ __launch_bounds__(256) void k_fused(int* __restrict__ rowptr,
                                               const int* __restrict__ bsum, int n,
                                               const float* __restrict__ X,
                                               const float* __restrict__ W,
                                               const float* __restrict__ scale,
                                               __half* __restrict__ Y, int M,
                                               int FB, int GB,
                                               const int* __restrict__ praw,
                                               const int* __restrict__ row,
                                               const int* __restrict__ col,
                                               const int* __restrict__ rank,
                                               int* __restrict__ csr, int E) {
    __shared__ __align__(16) __half2 wt[128 * 64];  // 32 KB (gemm); reused by fix/fill
    int b = blockIdx.x, tid = threadIdx.x;
    if (b < FB) {
        int* red = (int*)wt;
        int partial = 0;
        for (int j = tid; j < b; j += 256) partial += bsum[j];
        red[tid] = partial;
        __syncthreads();
        for (int off = 128; off > 0; off >>= 1) {
            if (tid < off) red[tid] += red[tid + off];
            __syncthreads();
        }
        int offv = red[0];
        if (offv == 0) return;
#pragma unroll
        for (int r = 0; r < 4; ++r) {
            int i = b * 1024 + r * 256 + tid;
            if (i < n) rowptr[i + 1] += offv;
        }
        return;
    }
    if (b >= FB + GB) {
        // ---- fill range: 1024 edges per block ----
        int* q = (int*)wt;  // Q[l] = sum bsum[0..l-1], l in [0,63]
        int nb = (n + 1023) >> 10;  // chunk count (<=49 here, <=64 supported)
        if (tid < 64) {
            int v = (tid >= 1 && tid <= nb) ? bsum[tid - 1] : 0;
#pragma unroll
            for (int off = 1; off < 64; off <<= 1) {
                int t = __shfl_up(v, off);
                if ((tid & 63) >= off) v += t;
            }
            q[tid] = v;  // inclusive scan of shifted bsum == exclusive prefix Q
        }
        __syncthreads();
        int base = (b - FB - GB) * 1024;
#pragma unroll
        for (int r = 0; r < 4; ++r) {
            int e = base + r * 256 + tid;
            if (e < E) {
                int c = col[e];
                int qi = (c == 0) ? 0 : ((c - 1) >> 10);  // praw[0]=0, Q[0]=0
                csr[praw[c] + q[qi] + rank[e]] = row[e];
            }
        }
        return;
    }
    gemm_tile<128, float>(X, W, scale, Y, M, (b - FB) * 64, wt, tid);
}

__global__ __launch_bounds__(256) void k_gemm2(const __half* __restrict__ X,
                                               const float* __restrict__ W,
                                               const float* __restrict__ scale,
                                               __half* __restrict__ Y, int M) {
    __shared__ __align__(16) __half2 wt[64 * 64];  // 16 KB
    gemm_tile<64, __half>(X, W, scale, Y, M, blockIdx.x * 64, wt, threadIdx.x);
}

// F=128: 4 nodes/wave (16 lanes x 16B = one 256B row per gather instr).
// Cooperative index load: one VMEM instr per 8 edges, __shfl redistribute.
__global__ __launch_bounds__(256) void k_agg128(const __half* __restrict__ xw,
                                                const float* __restrict__ dis,
                                                const int* __restrict__ rowptr,
                                                const int* __restrict__ csr,
                                                const float* __restrict__ bias,
                                                __half* __restrict__ out, int n) {
    int tid = threadIdx.x;
    int lane = tid & 63;
    int q = lane >> 4, li = lane & 15;
    int qbase = lane & 48;
    int node = blockIdx.x * 16 + ((tid >> 6) << 2) + q;
    bool ok = node < n;
    float di = 0.f;
    int beg = 0, end = 0;
    if (ok) {
        di = dis[node];
        beg = rowptr[node];
        end = rowptr[node + 1];
    }
    int dg = end - beg;
    int m1 = max(dg, __shfl(dg, lane ^ 16));
    int mx = max(m1, __shfl(m1, lane ^ 32));  // max over the wave's 4 nodes
    const half8* rows = (const half8*)xw;     // 16 half8 per row
    float acc[8] = {};
    if (ok) {
        half8 sf = rows[(size_t)node * 16 + li];
#pragma unroll
        for (int f = 0; f < 8; ++f) acc[f] = (float)sf[f];
    }
    for (int i = 0; i < mx; i += 8) {
        int e = beg + i + (li & 7);
        int myidx = (e < end) ? csr[e] : 0;  // one VMEM instr per 8 edges
        half8 v[8];
#pragma unroll
        for (int j = 0; j < 8; ++j) {
            int s = __shfl(myidx, qbase + j);
            v[j] = rows[(size_t)s * 16 + li];
        }
#pragma unroll
        for (int j = 0; j < 8; ++j) {
            if (beg + i + j < end) {
#pragma unroll
                for (int f = 0; f < 8; ++f) acc[f] += (float)v[j][f];
            }
        }
    }
    if (ok) {
        floatx4 b0 = *(const floatx4*)&bias[li * 8];
        floatx4 b1 = *(const floatx4*)&bias[li * 8 + 4];
        half8 o;
#pragma unroll
        for (int f = 0; f < 4; ++f) o[f] = (_Float16)fmaxf(acc[f] * di + b0[f], 0.f);
#pragma unroll
        for (int f = 0; f < 4; ++f) o[4 + f] = (_Float16)fmaxf(acc[4 + f] * di + b1[f], 0.f);
        ((half8*)out)[(size_t)node * 16 + li] = o;
    }
}

// F=64: 8 nodes/wave (8 lanes x 16B = one 128B row per gather instr).
__global__ __launch_bounds__(256) void k_agg64(const __half* __restrict__ xw,
                                               const float* __restrict__ dis,
                                               const int* __restrict__ rowptr,
                                               const int* __restrict__ csr,
                                               const float* __restrict__ bias,
                                               float* __restrict__ out, int n) {
    int tid = threadIdx.x;
    int lane = tid & 63;
    int o8 = lane >> 3, li = lane & 7;
    int obase = lane & 56;
    int node = blockIdx.x * 32 + ((tid >> 6) << 3) + o8;
    bool ok = node < n;
    float di = 0.f;
    int beg = 0, end = 0;
    if (ok) {
        di = dis[node];
        beg = rowptr[node];
        end = rowptr[node + 1];
    }
    int dg = end - beg;
    int m1 = max(dg, __shfl(dg, lane ^ 8));
    int m2 = max(m1, __shfl(m1, lane ^ 16));
    int mx = max(m2, __shfl(m2, lane ^ 32));  // max over the wave's 8 nodes
    const half8* rows = (const half8*)xw;     // 8 half8 per row
    float acc[8] = {};
    if (ok) {
        half8 sf = rows[(size_t)node * 8 + li];
#pragma unroll
        for (int f = 0; f < 8; ++f) acc[f] = (float)sf[f];
    }
    for (int i = 0; i < mx; i += 8) {
        int e = beg + i + li;
        int myidx = (e < end) ? csr[e] : 0;  // one VMEM instr per 8 edges
        half8 v[8];
#pragma unroll
        for (int j = 0; j < 8; ++j) {
            int s = __shfl(myidx, obase + j);
            v[j] = rows[(size_t)s * 8 + li];
        }
#pragma unroll
        for (int j = 0; j < 8; ++j) {
            if (beg + i + j < end) {
#pragma unroll
                for (int f = 0; f < 8; ++f) acc[f] += (float)v[j][f];
            }
        }
    }
    if (ok) {
        floatx4 b0 = *(const floatx4*)&bias[li * 8];
        floatx4 b1 = *(const floatx4*)&bias[li * 8 + 4];
        floatx4 o0, o1;
#pragma unroll
        for (int f = 0; f < 4; ++f) o0[f] = acc[f] * di + b0[f];
#pragma unroll
        for (int f = 0; f < 4; ++f) o1[f] = acc[4 + f] * di + b1[f];
        *(floatx4*)&out[(size_t)node * 64 + li * 8] = o0;
        *(floatx4*)&out[(size_t)node * 64 + li * 8 + 4] = o1;
    }
}

extern "C" void kernel_launch(void* const* d_in, const int* in_sizes, int n_in,
                              void* d_out, int out_size, void* d_ws, size_t ws_size,
                              hipStream_t stream) {
    const float* x  = (const float*)d_in[0];
    const int*   ei = (const int*)d_in[1];
    const float* W1 = (const float*)d_in[2];
    const float* b1 = (const float*)d_in[3];
    const float* W2 = (const float*)d_in[4];
    const float* b2 = (const float*)d_in[5];
    float* out = (float*)d_out;

    const int n = in_sizes[0] / 128;   // 50000
    const int E = in_sizes[1] / 2;     // 800000
    const int* row = ei;
    const int* col = ei + E;
    const int NB = (n + 1023) / 1024;       // scan chunks (fix range)
    const int CB = (E + 255) / 256;
    const int GB = (n + 63) / 64;           // gemm1 blocks
    const int FILLB = (E + 1023) / 1024;    // fused fill blocks (1024 edges each)

    char* ws = (char*)d_ws;
    size_t off = 0;
    auto alloc = [&](size_t bytes) -> void* {
        void* p = ws + off;
        off += (bytes + 255) & ~(size_t)255;
        return p;
    };
    int*    deg    = (int*)alloc((size_t)n * 4);
    int*    rowptr = (int*)alloc((size_t)(n + 1) * 4);
    int*    praw   = (int*)alloc((size_t)(n + 1) * 4);
    int*    bsum   = (int*)alloc((size_t)NB * 4);
    int*    rank   = (int*)alloc((size_t)E * 4);
    int*    csr    = (int*)alloc((size_t)E * 4);
    float*  dis    = (float*)alloc((size_t)n * 4);
    __half* xw1    = (__half*)alloc((size_t)n * 128 * 2);
    __half* h      = (__half*)alloc((size_t)n * 128 * 2);
    __half* xw2    = (__half*)alloc((size_t)n * 64 * 2);
    (void)ws_size;

    hipMemsetAsync(deg, 0, (size_t)n * 4, stream);
    k_count<<<CB, 256, 0, stream>>>(col, deg, rank, E);
    k_scan_local<<<NB, 1024, 0, stream>>>(deg, rowptr, praw, bsum, dis, n);
    // fix || gemm1 || fill in one dispatch (independent resources; fill uses
    // praw + per-block bsum-prefix so it never reads the rowptr fix mutates).
    k_fused<<<NB + GB + FILLB, 256, 0, stream>>>(rowptr, bsum, n, x, W1, dis, xw1,
                                                 n, NB, GB, praw, row, col, rank,
                                                 csr, E);
    k_agg128<<<(n + 15) / 16, 256, 0, stream>>>(xw1, dis, rowptr, csr, b1, h, n);
    k_gemm2<<<GB, 256, 0, stream>>>(h, W2, dis, xw2, n);
    k_agg64<<<(n + 31) / 32, 256, 0, stream>>>(xw2, dis, rowptr, csr, b2, out, n);
}

// Round 5
// 198.836 us; speedup vs baseline: 1.3297x; 1.0148x over previous
//
#include <hip/hip_runtime.h>
#include <hip/hip_fp16.h>

// GCN 2-layer. count (+rank) -> multi-block shfl-scan (fused rsqrt) ->
// [fused scan_fix || MFMA gemm1 || CSR fill] -> [fused agg128+gemm2] -> agg64.
// out[i] = dis[i]*(scaled[i] + sum_j scaled[j]) + b, scaled[j]=dis[j]*(x@W)[j]
//
// r16: fuse agg128+gemm2 into k_agg_gemm (64 nodes/block: gather-agg ->
// LDS h-tile (XOR swizzle, <=2-way banks) -> MFMA -> xw2). Kills the h
// HBM round-trip (25.6MB), one dispatch boundary, and hides gemm2's MFMA
// under the agg gather latency. 7 -> 6 dispatches.
// r17: identical resubmit (r16 bench was an infra failure, no verdict;
// audited k_agg_gemm for fault risk: LDS bounds, barriers, gather guards
// all clean — same precedent as r13->r14).
// History: r7 weighted-CSR int2 -11us (reverted); r9 one-block scan 133us
// (reverted); r11 degree-bucket perm: atomic-contention disaster AND aggs
// unchanged (aggs at gather line-touch floor ~6.4cy/64B-line/CU, r14);
// r12 = shfl scan + fix||gemm1 (203us); r13/r14 sliced agg 264us
// (FALSIFIED: gather cost ~ unique lines touched, tier-independent);
// r15 = +fill fused (202us, neutral: fill ~40us was the long pole of that
// dispatch, gemm1 ~12us rode along free).

typedef _Float16 half8 __attribute__((ext_vector_type(8)));
typedef float floatx4 __attribute__((ext_vector_type(4)));

__global__ void k_count(const int* __restrict__ col, int* __restrict__ deg,
                        int* __restrict__ rank, int E) {
    int e = blockIdx.x * blockDim.x + threadIdx.x;
    if (e < E) rank[e] = atomicAdd(&deg[col[e]], 1);
}

// Per-chunk inclusive scan via wave shfl (2 barriers) + dis = rsqrt(deg+1).
// Writes rowptr (to be globally fixed) AND praw (raw copy for the fused
// fill, which applies the chunk prefix itself).
__global__ __launch_bounds__(1024) void k_scan_local(const int* __restrict__ deg,
                                                     int* __restrict__ rowptr,
                                                     int* __restrict__ praw,
                                                     int* __restrict__ bsum,
                                                     float* __restrict__ dis, int n) {
    __shared__ int wsum[16];
    int b = blockIdx.x, tid = threadIdx.x;
    int lane = tid & 63, w = tid >> 6;
    int i = b * 1024 + tid;
    int v = (i < n) ? deg[i] : 0;
    if (i < n) dis[i] = rsqrtf((float)v + 1.0f);  // +1 = self-loop
    int sc = v;
#pragma unroll
    for (int off = 1; off < 64; off <<= 1) {
        int t = __shfl_up(sc, off);
        if (lane >= off) sc += t;
    }
    if (lane == 63) wsum[w] = sc;
    __syncthreads();
    if (w == 0) {
        int s = (lane < 16) ? wsum[lane] : 0;
#pragma unroll
        for (int off = 1; off < 16; off <<= 1) {
            int t = __shfl_up(s, off);
            if (lane >= off) s += t;
        }
        if (lane < 16) wsum[lane] = s;
    }
    __syncthreads();
    int incl = sc + ((w > 0) ? wsum[w - 1] : 0);
    if (i < n) {
        rowptr[i + 1] = incl;
        praw[i + 1] = incl;
    }
    if (tid == 1023) bsum[b] = incl;
    if (b == 0 && tid == 0) {
        rowptr[0] = 0;
        praw[0] = 0;
    }
}

// Y[M,N](fp16) = (X[M,128] @ W[128,N]) * scale[m].
// Block: 64 rows (4 waves x 16), all N cols. K=128 in 4 MFMA steps of 32.
// LDS Wt[n][k] fp16 as half2 dwords; 16B block (n,kblk) at dword
// n*64 + (kblk ^ (n&15))*4 (XOR swizzle -> <=2-way banks on b128 reads).
// Frags (m89/m118/m120): A[m=lane&15][k=quad*8+j], B[k=quad*8+j][n=lane&15],
// D row=quad*4+reg, col=lane&15.
template <int N, typename AT>
__device__ __forceinline__ void gemm_tile(const AT* __restrict__ X,
                                          const float* __restrict__ W,
                                          const float* __restrict__ scale,
                                          __half* __restrict__ Y, int M,
                                          int m0, __half2* wt, int tid) {
    for (int i = tid; i < N * 64; i += 256) {
        int nn = i & (N - 1);
        int k2 = i / N;  // k = 2*k2
        float w0 = W[(size_t)(2 * k2) * N + nn];
        float w1 = W[(size_t)(2 * k2 + 1) * N + nn];
        wt[nn * 64 + ((k2 >> 2) ^ (nn & 15)) * 4 + (k2 & 3)] = __floats2half2_rn(w0, w1);
    }
    __syncthreads();
    int wid = tid >> 6, lane = tid & 63;
    int col = lane & 15, quad = lane >> 4;
    int m_a = m0 + wid * 16 + col;
    bool a_ok = m_a < M;
    constexpr int NT = N / 16;
    floatx4 acc[NT] = {};
#pragma unroll
    for (int ks = 0; ks < 4; ++ks) {
        int k = ks * 32 + quad * 8;
        half8 af;
        if constexpr (sizeof(AT) == 4) {
            floatx4 a0 = {0.f, 0.f, 0.f, 0.f}, a1 = {0.f, 0.f, 0.f, 0.f};
            if (a_ok) {
                a0 = *(const floatx4*)&X[(size_t)m_a * 128 + k];
                a1 = *(const floatx4*)&X[(size_t)m_a * 128 + k + 4];
            }
            af = half8{(_Float16)a0[0], (_Float16)a0[1], (_Float16)a0[2], (_Float16)a0[3],
                       (_Float16)a1[0], (_Float16)a1[1], (_Float16)a1[2], (_Float16)a1[3]};
        } else {
            half8 t = {};
            if (a_ok) t = *(const half8*)(const void*)&X[(size_t)m_a * 128 + k];
            af = t;
        }
        int kblk = ks * 4 + quad;
#pragma unroll
        for (int nt = 0; nt < NT; ++nt) {
            int nn = nt * 16 + col;
            half8 bf = *(const half8*)(const void*)&wt[nn * 64 + (kblk ^ (nn & 15)) * 4];
            acc[nt] = __builtin_amdgcn_mfma_f32_16x16x32_f16(af, bf, acc[nt], 0, 0, 0);
        }
    }
    int mbase = m0 + wid * 16 + quad * 4;
    float s[4];
#pragma unroll
    for (int r = 0; r < 4; ++r) s[r] = (mbase + r < M) ? scale[mbase + r] : 0.f;
#pragma unroll
    for (int nt = 0; nt < NT; ++nt) {
#pragma unroll
        for (int r = 0; r < 4; ++r) {
            if (mbase + r < M)
                Y[(size_t)(mbase + r) * N + nt * 16 + col] = __float2half(acc[nt][r] * s[r]);
        }
    }
}

// Fused 3-range kernel:
//   blocks [0,FB):        scan_fix — add chunk prefix to rowptr (for aggs)
//   blocks [FB,FB+GB):    gemm1 (MFMA)
//   blocks [FB+GB,...):   CSR fill — pos = praw[c] + Q[(c-1)>>10] + rank[e],
//                         Q scanned from bsum in LDS (no dep on fix; praw is
//                         a separate copy so concurrent fix can't race).
__global__ __launch_bounds__(256) void k_fused(int* __restrict__ rowptr,
                                               const int* __restrict__ bsum, int n,
                                               const float* __restrict__ X,
                                               const float* __restrict__ W,
                                               const float* __restrict__ scale,
                                               __half* __restrict__ Y, int M,
                                               int FB, int GB,
                                               const int* __restrict__ praw,
                                               const int* __restrict__ row,
                                               const int* __restrict__ col,
                                               const int* __restrict__ rank,
                                               int* __restrict__ csr, int E) {
    __shared__ __align__(16) __half2 wt[128 * 64];  // 32 KB (gemm); reused by fix/fill
    int b = blockIdx.x, tid = threadIdx.x;
    if (b < FB) {
        int* red = (int*)wt;
        int partial = 0;
        for (int j = tid; j < b; j += 256) partial += bsum[j];
        red[tid] = partial;
        __syncthreads();
        for (int off = 128; off > 0; off >>= 1) {
            if (tid < off) red[tid] += red[tid + off];
            __syncthreads();
        }
        int offv = red[0];
        if (offv == 0) return;
#pragma unroll
        for (int r = 0; r < 4; ++r) {
            int i = b * 1024 + r * 256 + tid;
            if (i < n) rowptr[i + 1] += offv;
        }
        return;
    }
    if (b >= FB + GB) {
        // ---- fill range: 1024 edges per block ----
        int* q = (int*)wt;  // Q[l] = sum bsum[0..l-1], l in [0,63]
        int nb = (n + 1023) >> 10;  // chunk count (<=49 here, <=64 supported)
        if (tid < 64) {
            int v = (tid >= 1 && tid <= nb) ? bsum[tid - 1] : 0;
#pragma unroll
            for (int off = 1; off < 64; off <<= 1) {
                int t = __shfl_up(v, off);
                if ((tid & 63) >= off) v += t;
            }
            q[tid] = v;  // inclusive scan of shifted bsum == exclusive prefix Q
        }
        __syncthreads();
        int base = (b - FB - GB) * 1024;
#pragma unroll
        for (int r = 0; r < 4; ++r) {
            int e = base + r * 256 + tid;
            if (e < E) {
                int c = col[e];
                int qi = (c == 0) ? 0 : ((c - 1) >> 10);  // praw[0]=0, Q[0]=0
                csr[praw[c] + q[qi] + rank[e]] = row[e];
            }
        }
        return;
    }
    gemm_tile<128, float>(X, W, scale, Y, M, (b - FB) * 64, wt, tid);
}

// Fused agg128 + gemm2. Block = 64 nodes (4 agg sub-phases of 16 nodes),
// then xw2[64,64] = (h_tile @ W2) * dis via MFMA.
// Agg: 4 nodes/wave (quad per node; 16 lanes x 16B = one 256B row per
// gather instr), cooperative csr load (1 VMEM / 8 edges, shfl spread).
// h_tile row m stored in LDS with 16B-slot XOR swizzle slot^=(m&7):
// agg writes lane li -> slot li^(m&7); gemm A-read slot (ks*4+quad)^(m&7)
// -> <=2-way banks both ways (G4). relu(acc*di+b1) applied before store.
__global__ __launch_bounds__(256) void k_agg_gemm(const __half* __restrict__ xw,
                                                  const float* __restrict__ dis,
                                                  const int* __restrict__ rowptr,
                                                  const int* __restrict__ csr,
                                                  const float* __restrict__ bias,
                                                  const float* __restrict__ W2,
                                                  __half* __restrict__ Y,  // xw2 [n,64]
                                                  int n) {
    __shared__ __align__(16) half8 htile[64 * 16];   // 16 KB
    __shared__ __align__(16) __half2 wt[64 * 64];    // 16 KB
    int tid = threadIdx.x, b = blockIdx.x;
    int lane = tid & 63, w = tid >> 6;
    int q = lane >> 4, li = lane & 15;
    int qbase = lane & 48;

    // Stage W2 -> LDS (overlaps the first agg phase's latency).
    for (int i = tid; i < 64 * 64; i += 256) {
        int nn = i & 63;
        int k2 = i >> 6;  // k = 2*k2
        float w0 = W2[(size_t)(2 * k2) * 64 + nn];
        float w1 = W2[(size_t)(2 * k2 + 1) * 64 + nn];
        wt[nn * 64 + ((k2 >> 2) ^ (nn & 15)) * 4 + (k2 & 3)] = __floats2half2_rn(w0, w1);
    }

    const half8* rows = (const half8*)xw;  // 16 half8 per row
    floatx4 bb0 = *(const floatx4*)&bias[li * 8];
    floatx4 bb1 = *(const floatx4*)&bias[li * 8 + 4];

#pragma unroll
    for (int g = 0; g < 4; ++g) {
        int m_loc = g * 16 + (w << 2) + q;     // local row 0..63
        int node = b * 64 + m_loc;
        bool ok = node < n;
        float di = 0.f;
        int beg = 0, end = 0;
        if (ok) {
            di = dis[node];
            beg = rowptr[node];
            end = rowptr[node + 1];
        }
        int dg = end - beg;
        int m1 = max(dg, __shfl(dg, lane ^ 16));
        int mx = max(m1, __shfl(m1, lane ^ 32));  // max over the wave's 4 nodes
        float acc[8] = {};
        if (ok) {
            half8 sf = rows[(size_t)node * 16 + li];
#pragma unroll
            for (int f = 0; f < 8; ++f) acc[f] = (float)sf[f];
        }
        for (int i = 0; i < mx; i += 8) {
            int e = beg + i + (li & 7);
            int myidx = (e < end) ? csr[e] : 0;  // one VMEM instr per 8 edges
            half8 v[8];
#pragma unroll
            for (int j = 0; j < 8; ++j) {
                int s = __shfl(myidx, qbase + j);
                v[j] = rows[(size_t)s * 16 + li];
            }
#pragma unroll
            for (int j = 0; j < 8; ++j) {
                if (beg + i + j < end) {
#pragma unroll
                    for (int f = 0; f < 8; ++f) acc[f] += (float)v[j][f];
                }
            }
        }
        half8 o = {};
        if (ok) {
#pragma unroll
            for (int f = 0; f < 4; ++f) o[f] = (_Float16)fmaxf(acc[f] * di + bb0[f], 0.f);
#pragma unroll
            for (int f = 0; f < 4; ++f) o[4 + f] = (_Float16)fmaxf(acc[4 + f] * di + bb1[f], 0.f);
        }
        htile[m_loc * 16 + (li ^ (m_loc & 7))] = o;
    }
    __syncthreads();

    // GEMM phase: A from htile (swizzled), B from wt.
    int col16 = lane & 15, quad = lane >> 4;
    int m_loc = w * 16 + col16;
    floatx4 gacc[4] = {};
#pragma unroll
    for (int ks = 0; ks < 4; ++ks) {
        half8 af = htile[m_loc * 16 + ((ks * 4 + quad) ^ (m_loc & 7))];
        int kblk = ks * 4 + quad;
#pragma unroll
        for (int nt = 0; nt < 4; ++nt) {
            int nn = nt * 16 + col16;
            half8 bf = *(const half8*)(const void*)&wt[nn * 64 + (kblk ^ (nn & 15)) * 4];
            gacc[nt] = __builtin_amdgcn_mfma_f32_16x16x32_f16(af, bf, gacc[nt], 0, 0, 0);
        }
    }
    int mbase = b * 64 + w * 16 + quad * 4;
    float s[4];
#pragma unroll
    for (int r = 0; r < 4; ++r) s[r] = (mbase + r < n) ? dis[mbase + r] : 0.f;
#pragma unroll
    for (int nt = 0; nt < 4; ++nt) {
#pragma unroll
        for (int r = 0; r < 4; ++r) {
            if (mbase + r < n)
                Y[(size_t)(mbase + r) * 64 + nt * 16 + col16] = __float2half(gacc[nt][r] * s[r]);
        }
    }
}

// F=64: 8 nodes/wave (8 lanes x 16B = one 128B row per gather instr).
__global__ __launch_bounds__(256) void k_agg64(const __half* __restrict__ xw,
                                               const float* __restrict__ dis,
                                               const int* __restrict__ rowptr,
                                               const int* __restrict__ csr,
                                               const float* __restrict__ bias,
                                               float* __restrict__ out, int n) {
    int tid = threadIdx.x;
    int lane = tid & 63;
    int o8 = lane >> 3, li = lane & 7;
    int obase = lane & 56;
    int node = blockIdx.x * 32 + ((tid >> 6) << 3) + o8;
    bool ok = node < n;
    float di = 0.f;
    int beg = 0, end = 0;
    if (ok) {
        di = dis[node];
        beg = rowptr[node];
        end = rowptr[node + 1];
    }
    int dg = end - beg;
    int m1 = max(dg, __shfl(dg, lane ^ 8));
    int m2 = max(m1, __shfl(m1, lane ^ 16));
    int mx = max(m2, __shfl(m2, lane ^ 32));  // max over the wave's 8 nodes
    const half8* rows = (const half8*)xw;     // 8 half8 per row
    float acc[8] = {};
    if (ok) {
        half8 sf = rows[(size_t)node * 8 + li];
#pragma unroll
        for (int f = 0; f < 8; ++f) acc[f] = (float)sf[f];
    }
    for (int i = 0; i < mx; i += 8) {
        int e = beg + i + li;
        int myidx = (e < end) ? csr[e] : 0;  // one VMEM instr per 8 edges
        half8 v[8];
#pragma unroll
        for (int j = 0; j < 8; ++j) {
            int s = __shfl(myidx, obase + j);
            v[j] = rows[(size_t)s * 8 + li];
        }
#pragma unroll
        for (int j = 0; j < 8; ++j) {
            if (beg + i + j < end) {
#pragma unroll
                for (int f = 0; f < 8; ++f) acc[f] += (float)v[j][f];
            }
        }
    }
    if (ok) {
        floatx4 b0 = *(const floatx4*)&bias[li * 8];
        floatx4 b1 = *(const floatx4*)&bias[li * 8 + 4];
        floatx4 o0, o1;
#pragma unroll
        for (int f = 0; f < 4; ++f) o0[f] = acc[f] * di + b0[f];
#pragma unroll
        for (int f = 0; f < 4; ++f) o1[f] = acc[4 + f] * di + b1[f];
        *(floatx4*)&out[(size_t)node * 64 + li * 8] = o0;
        *(floatx4*)&out[(size_t)node * 64 + li * 8 + 4] = o1;
    }
}

extern "C" void kernel_launch(void* const* d_in, const int* in_sizes, int n_in,
                              void* d_out, int out_size, void* d_ws, size_t ws_size,
                              hipStream_t stream) {
    const float* x  = (const float*)d_in[0];
    const int*   ei = (const int*)d_in[1];
    const float* W1 = (const float*)d_in[2];
    const float* b1 = (const float*)d_in[3];
    const float* W2 = (const float*)d_in[4];
    const float* b2 = (const float*)d_in[5];
    float* out = (float*)d_out;

    const int n = in_sizes[0] / 128;   // 50000
    const int E = in_sizes[1] / 2;     // 800000
    const int* row = ei;
    const int* col = ei + E;
    const int NB = (n + 1023) / 1024;       // scan chunks (fix range)
    const int CB = (E + 255) / 256;
    const int GB = (n + 63) / 64;           // gemm1 / agg_gemm blocks
    const int FILLB = (E + 1023) / 1024;    // fused fill blocks (1024 edges each)

    char* ws = (char*)d_ws;
    size_t off = 0;
    auto alloc = [&](size_t bytes) -> void* {
        void* p = ws + off;
        off += (bytes + 255) & ~(size_t)255;
        return p;
    };
    int*    deg    = (int*)alloc((size_t)n * 4);
    int*    rowptr = (int*)alloc((size_t)(n + 1) * 4);
    int*    praw   = (int*)alloc((size_t)(n + 1) * 4);
    int*    bsum   = (int*)alloc((size_t)NB * 4);
    int*    rank   = (int*)alloc((size_t)E * 4);
    int*    csr    = (int*)alloc((size_t)E * 4);
    float*  dis    = (float*)alloc((size_t)n * 4);
    __half* xw1    = (__half*)alloc((size_t)n * 128 * 2);
    __half* xw2    = (__half*)alloc((size_t)n * 64 * 2);
    (void)ws_size;

    hipMemsetAsync(deg, 0, (size_t)n * 4, stream);
    k_count<<<CB, 256, 0, stream>>>(col, deg, rank, E);
    k_scan_local<<<NB, 1024, 0, stream>>>(deg, rowptr, praw, bsum, dis, n);
    // fix || gemm1 || fill in one dispatch (independent resources; fill uses
    // praw + per-block bsum-prefix so it never reads the rowptr fix mutates).
    k_fused<<<NB + GB + FILLB, 256, 0, stream>>>(rowptr, bsum, n, x, W1, dis, xw1,
                                                 n, NB, GB, praw, row, col, rank,
                                                 csr, E);
    // agg128 + gemm2 fused: h never touches HBM.
    k_agg_gemm<<<GB, 256, 0, stream>>>(xw1, dis, rowptr, csr, b1, W2, xw2, n);
    k_agg64<<<(n + 31) / 32, 256, 0, stream>>>(xw2, dis, rowptr, csr, b2, out, n);
}